// Round 4
// baseline (341.323 us; speedup 1.0000x reference)
//
#include <hip/hip_runtime.h>
#include <hip/hip_bf16.h>
#include <stdint.h>

#define R_ 8
#define N_ 8192
#define D_ 2048
#define A_ 128
#define J_ 1024          // R_*A_
#define LN_EPS 1e-5f
#define GEMM_BLOCKS 512  // 64 m-tiles x 8 routers

typedef __attribute__((ext_vector_type(8))) short bf16x8;   // 8 bf16 in 4 VGPRs
typedef __attribute__((ext_vector_type(4))) float f32x4;

__device__ inline ushort f2bf(float f) {
    union { float f; uint32_t u; } v; v.f = f;
    uint32_t u = v.u;
    return (ushort)((u + 0x7fffu + ((u >> 16) & 1u)) >> 16);   // RNE
}
__device__ inline float bf2f(ushort u) {
    union { uint32_t u; float f; } v; v.u = ((uint32_t)u) << 16;
    return v.f;
}

// ---------------------------------------------------------------------------
// k_prep: blocks [0,N_)   : row-LN stats of x -> xhat bf16 (shared by routers)
//         blocks [N_,N_+J_): weight-LN column j -> Bt bf16 (K-major) + cvec
// ---------------------------------------------------------------------------
__global__ __launch_bounds__(256) void k_prep(
    const float* __restrict__ x,
    const float* __restrict__ W,
    const float* __restrict__ ln_w,
    const float* __restrict__ ln_b,
    const float* __restrict__ rw_w,
    const float* __restrict__ rw_b,
    const float* __restrict__ rbias,
    ushort* __restrict__ xhat,
    ushort* __restrict__ Bt,
    float* __restrict__ cvec)
{
    __shared__ float sm[16];
    const int t = threadIdx.x;

    if (blockIdx.x < N_) {
        const int n = blockIdx.x;
        const float* xr = x + (size_t)n * D_;
        float4 v0 = *(const float4*)(xr + t * 4);
        float4 v1 = *(const float4*)(xr + 1024 + t * 4);
        float s  = v0.x + v0.y + v0.z + v0.w + v1.x + v1.y + v1.z + v1.w;
        float sq = v0.x*v0.x + v0.y*v0.y + v0.z*v0.z + v0.w*v0.w
                 + v1.x*v1.x + v1.y*v1.y + v1.z*v1.z + v1.w*v1.w;
        #pragma unroll
        for (int o = 32; o > 0; o >>= 1) {
            s  += __shfl_xor(s,  o, 64);
            sq += __shfl_xor(sq, o, 64);
        }
        if ((t & 63) == 0) { sm[t >> 6] = s; sm[8 + (t >> 6)] = sq; }
        __syncthreads();
        s  = sm[0] + sm[1] + sm[2] + sm[3];
        sq = sm[8] + sm[9] + sm[10] + sm[11];
        const float mean = s * (1.0f / D_);
        const float var  = sq * (1.0f / D_) - mean * mean;
        const float rstd = rsqrtf(var + LN_EPS);

        ushort4 p0 = make_ushort4(f2bf((v0.x - mean) * rstd), f2bf((v0.y - mean) * rstd),
                                  f2bf((v0.z - mean) * rstd), f2bf((v0.w - mean) * rstd));
        ushort4 p1 = make_ushort4(f2bf((v1.x - mean) * rstd), f2bf((v1.y - mean) * rstd),
                                  f2bf((v1.z - mean) * rstd), f2bf((v1.w - mean) * rstd));
        *(ushort4*)(xhat + (size_t)n * D_ + t * 4)        = p0;
        *(ushort4*)(xhat + (size_t)n * D_ + 1024 + t * 4) = p1;
    } else {
        const int j = blockIdx.x - N_;
        const int r = j >> 7, a = j & 127;
        const float* Wc = W + (size_t)r * D_ * A_ + a;

        float vals[8];
        float s = 0.f, sq = 0.f;
        #pragma unroll
        for (int k = 0; k < 8; ++k) {
            float v = Wc[(size_t)(t + k * 256) * A_];
            vals[k] = v; s += v; sq += v * v;
        }
        #pragma unroll
        for (int o = 32; o > 0; o >>= 1) {
            s  += __shfl_xor(s,  o, 64);
            sq += __shfl_xor(sq, o, 64);
        }
        if ((t & 63) == 0) { sm[t >> 6] = s; sm[8 + (t >> 6)] = sq; }
        __syncthreads();
        s  = sm[0] + sm[1] + sm[2] + sm[3];
        sq = sm[8] + sm[9] + sm[10] + sm[11];
        const float mean = s * (1.0f / D_);
        const float var  = sq * (1.0f / D_) - mean * mean;
        const float rstd = rsqrtf(var + LN_EPS);

        float cp = 0.f;
        #pragma unroll
        for (int k = 0; k < 8; ++k) {
            const int d = t + k * 256;
            const float nv = (vals[k] - mean) * rstd * rw_w[(size_t)r * D_ + d]
                           + rw_b[(size_t)r * D_ + d];
            Bt[(size_t)j * D_ + d] = f2bf(ln_w[(size_t)r * D_ + d] * nv);
            cp += ln_b[(size_t)r * D_ + d] * nv;
        }
        __syncthreads();   // sm reuse
        #pragma unroll
        for (int o = 32; o > 0; o >>= 1) cp += __shfl_xor(cp, o, 64);
        if ((t & 63) == 0) sm[t >> 6] = cp;
        __syncthreads();
        if (t == 0) cvec[j] = sm[0] + sm[1] + sm[2] + sm[3] + rbias[(size_t)r * A_ + a];
    }
}

// ---------------------------------------------------------------------------
// k_main: NO LDS, NO BARRIERS anywhere.
//   blocks [0,512)    : GEMM (mt = bid&63, r = bid>>6 -> all 8 routers of an
//                       m-tile share an XCD; xhat slab read once into L2).
//                       Fragments loaded DIRECTLY from global (L2/L3-hot),
//                       A ping-pong double-buffered; softmax fused epilogue.
//   blocks [512,8704) : new_x row writers — pure 512 MiB store stream, never
//                       blocked by the GEMM (no coupling points).
// ---------------------------------------------------------------------------
__global__ __launch_bounds__(256) void k_main(
    const ushort* __restrict__ Xh,
    const ushort* __restrict__ Bt,
    const float* __restrict__ cvec,
    const float* __restrict__ ln_w,
    const float* __restrict__ ln_b,
    float* __restrict__ new_x,
    float* __restrict__ logits,
    float* __restrict__ probs)
{
    const int t = threadIdx.x;

    if (blockIdx.x < GEMM_BLOCKS) {
        const int lane = t & 63;
        const int w    = t >> 6;             // wave 0..3, rows w*32..+31
        const int mt   = blockIdx.x & 63;
        const int r    = blockIdx.x >> 6;
        const int m0   = mt * 128;
        const int j0   = r * 128;

        // fragment base pointers (A: row m0+w*32+(lane&15), k-chunk (lane>>4)*8)
        const ushort* pA = Xh + (size_t)(m0 + w * 32 + (lane & 15)) * D_ + ((lane >> 4) << 3);
        const ushort* pB = Bt + (size_t)(j0 + (lane & 15)) * D_ + ((lane >> 4) << 3);

        f32x4 acc[2][8];
        #pragma unroll
        for (int mi = 0; mi < 2; ++mi)
            #pragma unroll
            for (int jf = 0; jf < 8; ++jf)
                acc[mi][jf] = (f32x4){0.f, 0.f, 0.f, 0.f};

        bf16x8 aP[2], aQ[2], bP[8];

        auto loadA = [&](bf16x8 (&af)[2], int kk) {
            af[0] = *(const bf16x8*)(pA + kk * 32);
            af[1] = *(const bf16x8*)(pA + 16 * D_ + kk * 32);
        };
        auto step = [&](bf16x8 (&af)[2], int kk) {
            #pragma unroll
            for (int jf = 0; jf < 8; ++jf)
                bP[jf] = *(const bf16x8*)(pB + (size_t)jf * 16 * D_ + kk * 32);
            #pragma unroll
            for (int jf = 0; jf < 8; ++jf) {
                acc[0][jf] = __builtin_amdgcn_mfma_f32_16x16x32_bf16(af[0], bP[jf], acc[0][jf], 0, 0, 0);
                acc[1][jf] = __builtin_amdgcn_mfma_f32_16x16x32_bf16(af[1], bP[jf], acc[1][jf], 0, 0, 0);
            }
        };

        loadA(aP, 0);
        for (int kt = 0; kt < 62; kt += 2) {
            loadA(aQ, kt + 1);
            step(aP, kt);
            loadA(aP, kt + 2);
            step(aQ, kt + 1);
        }
        loadA(aQ, 63);
        step(aP, 62);
        step(aQ, 63);

        // Epilogue: bias + row softmax (j-tile == router r's full A=128).
        // C/D layout: col = lane&15, row = (lane>>4)*4 + reg.
        float cv[8];
        #pragma unroll
        for (int jf = 0; jf < 8; ++jf) cv[jf] = cvec[j0 + jf * 16 + (lane & 15)];

        #pragma unroll
        for (int mi = 0; mi < 2; ++mi) {
            #pragma unroll
            for (int reg = 0; reg < 4; ++reg) {
                const int row = m0 + w * 32 + mi * 16 + (lane >> 4) * 4 + reg;
                float v[8], e[8];
                float mx = -3.4e38f;
                #pragma unroll
                for (int jf = 0; jf < 8; ++jf) {
                    v[jf] = acc[mi][jf][reg] + cv[jf];
                    mx = fmaxf(mx, v[jf]);
                }
                #pragma unroll
                for (int o = 8; o > 0; o >>= 1) mx = fmaxf(mx, __shfl_xor(mx, o, 64));
                float ssum = 0.f;
                #pragma unroll
                for (int jf = 0; jf < 8; ++jf) { e[jf] = __expf(v[jf] - mx); ssum += e[jf]; }
                #pragma unroll
                for (int o = 8; o > 0; o >>= 1) ssum += __shfl_xor(ssum, o, 64);
                const float inv = 1.0f / ssum;
                float* lrow = logits + ((size_t)r * N_ + row) * A_;
                float* prow = probs  + ((size_t)r * N_ + row) * A_;
                #pragma unroll
                for (int jf = 0; jf < 8; ++jf) {
                    const int aa = jf * 16 + (lane & 15);
                    lrow[aa] = v[jf];
                    prow[aa] = e[jf] * inv;
                }
            }
        }
    } else {
        // new_x writer: one block per row n; thread t owns cols [t*8, t*8+8)
        const int n = blockIdx.x - GEMM_BLOCKS;
        const bf16x8 h = *(const bf16x8*)(Xh + (size_t)n * D_ + t * 8);
        float hf[8];
        #pragma unroll
        for (int i = 0; i < 8; ++i) hf[i] = bf2f((ushort)h[i]);

        #pragma unroll
        for (int r = 0; r < R_; ++r) {
            const float* wr = ln_w + (size_t)r * D_ + t * 8;
            const float* br = ln_b + (size_t)r * D_ + t * 8;
            const float4 w0 = *(const float4*)(wr);
            const float4 w1 = *(const float4*)(wr + 4);
            const float4 b0 = *(const float4*)(br);
            const float4 b1 = *(const float4*)(br + 4);
            float4 o0, o1;
            o0.x = hf[0] * w0.x + b0.x; o0.y = hf[1] * w0.y + b0.y;
            o0.z = hf[2] * w0.z + b0.z; o0.w = hf[3] * w0.w + b0.w;
            o1.x = hf[4] * w1.x + b1.x; o1.y = hf[5] * w1.y + b1.y;
            o1.z = hf[6] * w1.z + b1.z; o1.w = hf[7] * w1.w + b1.w;
            float* dst = new_x + ((size_t)r * N_ + n) * D_ + t * 8;
            *(float4*)(dst)     = o0;
            *(float4*)(dst + 4) = o1;
        }
    }
}

// ---------------------------------------------------------------------------
extern "C" void kernel_launch(void* const* d_in, const int* in_sizes, int n_in,
                              void* d_out, int out_size, void* d_ws, size_t ws_size,
                              hipStream_t stream)
{
    const float* x     = (const float*)d_in[0];
    const float* ln_w  = (const float*)d_in[1];
    const float* ln_b  = (const float*)d_in[2];
    const float* W     = (const float*)d_in[3];
    const float* rw_w  = (const float*)d_in[4];
    const float* rw_b  = (const float*)d_in[5];
    const float* rbias = (const float*)d_in[6];

    float* out    = (float*)d_out;
    float* new_x  = out;                                   // [R,N,D]
    float* logits = out + (size_t)R_ * N_ * D_;            // [R,N,A]
    float* probs  = logits + (size_t)R_ * N_ * A_;         // [R,N,A]

    // ws: xhat bf16 [N][D] (32 MiB) | Bt bf16 [J][D] (4 MiB) | cvec f32 [J]
    ushort* xhat = (ushort*)d_ws;
    ushort* Btp  = (ushort*)((char*)d_ws + (size_t)N_ * D_ * 2);
    float*  cvec = (float*)((char*)d_ws + (size_t)N_ * D_ * 2 + (size_t)J_ * D_ * 2);

    hipLaunchKernelGGL(k_prep, dim3(N_ + J_), dim3(256), 0, stream,
                       x, W, ln_w, ln_b, rw_w, rw_b, rbias, xhat, Btp, cvec);
    hipLaunchKernelGGL(k_main, dim3(GEMM_BLOCKS + N_), dim3(256), 0, stream,
                       xhat, Btp, cvec, ln_w, ln_b, new_x, logits, probs);
}

// Round 5
// 242.884 us; speedup vs baseline: 1.4053x; 1.4053x over previous
//
#include <hip/hip_runtime.h>
#include <hip/hip_bf16.h>
#include <stdint.h>

#define R_ 8
#define N_ 8192
#define D_ 2048
#define A_ 128
#define J_ 1024          // R_*A_
#define LN_EPS 1e-5f
#define GEMM_BLOCKS 512  // 64 m-tiles x 8 routers

typedef __attribute__((ext_vector_type(8))) short bf16x8;   // 8 bf16 in 4 VGPRs
typedef __attribute__((ext_vector_type(4))) float f32x4;

__device__ inline ushort f2bf(float f) {
    union { float f; uint32_t u; } v; v.f = f;
    uint32_t u = v.u;
    return (ushort)((u + 0x7fffu + ((u >> 16) & 1u)) >> 16);   // RNE
}
__device__ inline float bf2f(ushort u) {
    union { uint32_t u; float f; } v; v.u = ((uint32_t)u) << 16;
    return v.f;
}

// ---------------------------------------------------------------------------
// k_prep: blocks [0,N_)   : row-LN stats of x -> xhat bf16 (shared by routers)
//         blocks [N_,N_+J_): weight-LN column j -> Bt bf16 (K-major) + cvec
// ---------------------------------------------------------------------------
__global__ __launch_bounds__(256) void k_prep(
    const float* __restrict__ x,
    const float* __restrict__ W,
    const float* __restrict__ ln_w,
    const float* __restrict__ ln_b,
    const float* __restrict__ rw_w,
    const float* __restrict__ rw_b,
    const float* __restrict__ rbias,
    ushort* __restrict__ xhat,
    ushort* __restrict__ Bt,
    float* __restrict__ cvec)
{
    __shared__ float sm[16];
    const int t = threadIdx.x;

    if (blockIdx.x < N_) {
        const int n = blockIdx.x;
        const float* xr = x + (size_t)n * D_;
        float4 v0 = *(const float4*)(xr + t * 4);
        float4 v1 = *(const float4*)(xr + 1024 + t * 4);
        float s  = v0.x + v0.y + v0.z + v0.w + v1.x + v1.y + v1.z + v1.w;
        float sq = v0.x*v0.x + v0.y*v0.y + v0.z*v0.z + v0.w*v0.w
                 + v1.x*v1.x + v1.y*v1.y + v1.z*v1.z + v1.w*v1.w;
        #pragma unroll
        for (int o = 32; o > 0; o >>= 1) {
            s  += __shfl_xor(s,  o, 64);
            sq += __shfl_xor(sq, o, 64);
        }
        if ((t & 63) == 0) { sm[t >> 6] = s; sm[8 + (t >> 6)] = sq; }
        __syncthreads();
        s  = sm[0] + sm[1] + sm[2] + sm[3];
        sq = sm[8] + sm[9] + sm[10] + sm[11];
        const float mean = s * (1.0f / D_);
        const float var  = sq * (1.0f / D_) - mean * mean;
        const float rstd = rsqrtf(var + LN_EPS);

        ushort4 p0 = make_ushort4(f2bf((v0.x - mean) * rstd), f2bf((v0.y - mean) * rstd),
                                  f2bf((v0.z - mean) * rstd), f2bf((v0.w - mean) * rstd));
        ushort4 p1 = make_ushort4(f2bf((v1.x - mean) * rstd), f2bf((v1.y - mean) * rstd),
                                  f2bf((v1.z - mean) * rstd), f2bf((v1.w - mean) * rstd));
        *(ushort4*)(xhat + (size_t)n * D_ + t * 4)        = p0;
        *(ushort4*)(xhat + (size_t)n * D_ + 1024 + t * 4) = p1;
    } else {
        const int j = blockIdx.x - N_;
        const int r = j >> 7, a = j & 127;
        const float* Wc = W + (size_t)r * D_ * A_ + a;

        float vals[8];
        float s = 0.f, sq = 0.f;
        #pragma unroll
        for (int k = 0; k < 8; ++k) {
            float v = Wc[(size_t)(t + k * 256) * A_];
            vals[k] = v; s += v; sq += v * v;
        }
        #pragma unroll
        for (int o = 32; o > 0; o >>= 1) {
            s  += __shfl_xor(s,  o, 64);
            sq += __shfl_xor(sq, o, 64);
        }
        if ((t & 63) == 0) { sm[t >> 6] = s; sm[8 + (t >> 6)] = sq; }
        __syncthreads();
        s  = sm[0] + sm[1] + sm[2] + sm[3];
        sq = sm[8] + sm[9] + sm[10] + sm[11];
        const float mean = s * (1.0f / D_);
        const float var  = sq * (1.0f / D_) - mean * mean;
        const float rstd = rsqrtf(var + LN_EPS);

        float cp = 0.f;
        #pragma unroll
        for (int k = 0; k < 8; ++k) {
            const int d = t + k * 256;
            const float nv = (vals[k] - mean) * rstd * rw_w[(size_t)r * D_ + d]
                           + rw_b[(size_t)r * D_ + d];
            Bt[(size_t)j * D_ + d] = f2bf(ln_w[(size_t)r * D_ + d] * nv);
            cp += ln_b[(size_t)r * D_ + d] * nv;
        }
        __syncthreads();   // sm reuse
        #pragma unroll
        for (int o = 32; o > 0; o >>= 1) cp += __shfl_xor(cp, o, 64);
        if ((t & 63) == 0) sm[t >> 6] = cp;
        __syncthreads();
        if (t == 0) cvec[j] = sm[0] + sm[1] + sm[2] + sm[3] + rbias[(size_t)r * A_ + a];
    }
}

// ---------------------------------------------------------------------------
// k_main: blocks [0,512)    : LDS-staged MFMA GEMM + fused softmax.
//           decode mt = bid&63, r = bid>>6  ->  XCD = bid%8 = mt%8: all 8
//           routers of an m-tile share an XCD, so each A-slab is fetched
//           from HBM ONCE and served 8x from that XCD's L2 (R2 fetched it
//           from 8 different XCDs = 256 MiB of HBM re-reads).
//         blocks [512,8704) : new_x row writers — pure store stream, no
//           barriers, never coupled to the GEMM's vmcnt drains (R3 lesson).
// ---------------------------------------------------------------------------
__global__ __launch_bounds__(256) void k_main(
    const ushort* __restrict__ Xh,
    const ushort* __restrict__ Bt,
    const float* __restrict__ cvec,
    const float* __restrict__ ln_w,
    const float* __restrict__ ln_b,
    float* __restrict__ new_x,
    float* __restrict__ logits,
    float* __restrict__ probs)
{
    __shared__ __attribute__((aligned(16))) ushort As[128 * 32];
    __shared__ __attribute__((aligned(16))) ushort Bs[128 * 32];
    const int t = threadIdx.x;

    if (blockIdx.x < GEMM_BLOCKS) {
        const int lane = t & 63;
        const int w    = t >> 6;                 // wave 0..3, rows w*32..+31
        const int mt   = blockIdx.x & 63;        // m-tile: XCD = mt%8
        const int r    = blockIdx.x >> 6;        // router
        const int m0   = mt * 128;
        const int j0   = r * 128;

        f32x4 acc[2][8];
        #pragma unroll
        for (int mi = 0; mi < 2; ++mi)
            #pragma unroll
            for (int jf = 0; jf < 8; ++jf)
                acc[mi][jf] = (f32x4){0.f, 0.f, 0.f, 0.f};

        for (int kt = 0; kt < D_ / 32; ++kt) {
            __syncthreads();                     // previous iter's reads done
            #pragma unroll
            for (int c = 0; c < 2; ++c) {
                const int q   = t + c * 256;     // 16B chunk index 0..511
                const int row = q >> 2;
                const int kc  = q & 3;
                const ushort* gA = Xh + (size_t)(m0 + row) * D_ + kt * 32 + kc * 8;
                __builtin_amdgcn_global_load_lds(
                    (const __attribute__((address_space(1))) void*)gA,
                    (__attribute__((address_space(3))) void*)(&As[q * 8]), 16, 0, 0);
                const ushort* gB = Bt + (size_t)(j0 + row) * D_ + kt * 32 + kc * 8;
                __builtin_amdgcn_global_load_lds(
                    (const __attribute__((address_space(1))) void*)gB,
                    (__attribute__((address_space(3))) void*)(&Bs[q * 8]), 16, 0, 0);
            }
            __syncthreads();                     // staging complete

            bf16x8 afr[2];
            #pragma unroll
            for (int mi = 0; mi < 2; ++mi)
                afr[mi] = *(const bf16x8*)(&As[(w * 32 + mi * 16 + (lane & 15)) * 32
                                               + (lane >> 4) * 8]);
            #pragma unroll
            for (int jf = 0; jf < 8; ++jf) {
                bf16x8 bfr = *(const bf16x8*)(&Bs[(jf * 16 + (lane & 15)) * 32
                                                  + (lane >> 4) * 8]);
                acc[0][jf] = __builtin_amdgcn_mfma_f32_16x16x32_bf16(afr[0], bfr, acc[0][jf], 0, 0, 0);
                acc[1][jf] = __builtin_amdgcn_mfma_f32_16x16x32_bf16(afr[1], bfr, acc[1][jf], 0, 0, 0);
            }
        }

        // Epilogue: bias + row softmax (j-tile == router r's full A=128).
        // C/D layout: col = lane&15, row = (lane>>4)*4 + reg.
        float cv[8];
        #pragma unroll
        for (int jf = 0; jf < 8; ++jf) cv[jf] = cvec[j0 + jf * 16 + (lane & 15)];

        #pragma unroll
        for (int mi = 0; mi < 2; ++mi) {
            #pragma unroll
            for (int reg = 0; reg < 4; ++reg) {
                const int row = m0 + w * 32 + mi * 16 + (lane >> 4) * 4 + reg;
                float v[8], e[8];
                float mx = -3.4e38f;
                #pragma unroll
                for (int jf = 0; jf < 8; ++jf) {
                    v[jf] = acc[mi][jf][reg] + cv[jf];
                    mx = fmaxf(mx, v[jf]);
                }
                #pragma unroll
                for (int o = 8; o > 0; o >>= 1) mx = fmaxf(mx, __shfl_xor(mx, o, 64));
                float ssum = 0.f;
                #pragma unroll
                for (int jf = 0; jf < 8; ++jf) { e[jf] = __expf(v[jf] - mx); ssum += e[jf]; }
                #pragma unroll
                for (int o = 8; o > 0; o >>= 1) ssum += __shfl_xor(ssum, o, 64);
                const float inv = 1.0f / ssum;
                float* lrow = logits + ((size_t)r * N_ + row) * A_;
                float* prow = probs  + ((size_t)r * N_ + row) * A_;
                #pragma unroll
                for (int jf = 0; jf < 8; ++jf) {
                    const int aa = jf * 16 + (lane & 15);
                    lrow[aa] = v[jf];
                    prow[aa] = e[jf] * inv;
                }
            }
        }
    } else {
        // new_x writer: one block per row n; thread t owns cols [t*8, t*8+8)
        const int n = blockIdx.x - GEMM_BLOCKS;
        const bf16x8 h = *(const bf16x8*)(Xh + (size_t)n * D_ + t * 8);
        float hf[8];
        #pragma unroll
        for (int i = 0; i < 8; ++i) hf[i] = bf2f((ushort)h[i]);

        #pragma unroll
        for (int r = 0; r < R_; ++r) {
            const float* wr = ln_w + (size_t)r * D_ + t * 8;
            const float* br = ln_b + (size_t)r * D_ + t * 8;
            const float4 w0 = *(const float4*)(wr);
            const float4 w1 = *(const float4*)(wr + 4);
            const float4 b0 = *(const float4*)(br);
            const float4 b1 = *(const float4*)(br + 4);
            float4 o0, o1;
            o0.x = hf[0] * w0.x + b0.x; o0.y = hf[1] * w0.y + b0.y;
            o0.z = hf[2] * w0.z + b0.z; o0.w = hf[3] * w0.w + b0.w;
            o1.x = hf[4] * w1.x + b1.x; o1.y = hf[5] * w1.y + b1.y;
            o1.z = hf[6] * w1.z + b1.z; o1.w = hf[7] * w1.w + b1.w;
            float* dst = new_x + ((size_t)r * N_ + n) * D_ + t * 8;
            *(float4*)(dst)     = o0;
            *(float4*)(dst + 4) = o1;
        }
    }
}

// ---------------------------------------------------------------------------
extern "C" void kernel_launch(void* const* d_in, const int* in_sizes, int n_in,
                              void* d_out, int out_size, void* d_ws, size_t ws_size,
                              hipStream_t stream)
{
    const float* x     = (const float*)d_in[0];
    const float* ln_w  = (const float*)d_in[1];
    const float* ln_b  = (const float*)d_in[2];
    const float* W     = (const float*)d_in[3];
    const float* rw_w  = (const float*)d_in[4];
    const float* rw_b  = (const float*)d_in[5];
    const float* rbias = (const float*)d_in[6];

    float* out    = (float*)d_out;
    float* new_x  = out;                                   // [R,N,D]
    float* logits = out + (size_t)R_ * N_ * D_;            // [R,N,A]
    float* probs  = logits + (size_t)R_ * N_ * A_;         // [R,N,A]

    // ws: xhat bf16 [N][D] (32 MiB) | Bt bf16 [J][D] (4 MiB) | cvec f32 [J]
    ushort* xhat = (ushort*)d_ws;
    ushort* Btp  = (ushort*)((char*)d_ws + (size_t)N_ * D_ * 2);
    float*  cvec = (float*)((char*)d_ws + (size_t)N_ * D_ * 2 + (size_t)J_ * D_ * 2);

    hipLaunchKernelGGL(k_prep, dim3(N_ + J_), dim3(256), 0, stream,
                       x, W, ln_w, ln_b, rw_w, rw_b, rbias, xhat, Btp, cvec);
    hipLaunchKernelGGL(k_main, dim3(GEMM_BLOCKS + N_), dim3(256), 0, stream,
                       xhat, Btp, cvec, ln_w, ln_b, new_x, logits, probs);
}

// Round 7
// 191.340 us; speedup vs baseline: 1.7839x; 1.2694x over previous
//
#include <hip/hip_runtime.h>
#include <hip/hip_bf16.h>
#include <stdint.h>

#define R_ 8
#define N_ 8192
#define D_ 2048
#define A_ 128
#define J_ 1024          // R_*A_
#define LN_EPS 1e-5f

typedef __attribute__((ext_vector_type(8))) short bf16x8;   // 8 bf16 in 4 VGPRs
typedef __attribute__((ext_vector_type(4))) float f32x4;

__device__ inline ushort f2bf(float f) {
    union { float f; uint32_t u; } v; v.f = f;
    uint32_t u = v.u;
    return (ushort)((u + 0x7fffu + ((u >> 16) & 1u)) >> 16);   // RNE
}
__device__ inline float bf2f(ushort u) {
    union { uint32_t u; float f; } v; v.u = ((uint32_t)u) << 16;
    return v.f;
}

// ---------------------------------------------------------------------------
// k_prep: blocks [0,N_)   : row-LN stats of x -> xhat bf16 (shared by routers)
//         blocks [N_,N_+J_): weight-LN column j -> Bt bf16 (K-major) + cvec
// ---------------------------------------------------------------------------
__global__ __launch_bounds__(256) void k_prep(
    const float* __restrict__ x,
    const float* __restrict__ W,
    const float* __restrict__ ln_w,
    const float* __restrict__ ln_b,
    const float* __restrict__ rw_w,
    const float* __restrict__ rw_b,
    const float* __restrict__ rbias,
    ushort* __restrict__ xhat,
    ushort* __restrict__ Bt,
    float* __restrict__ cvec)
{
    __shared__ float sm[16];
    const int t = threadIdx.x;

    if (blockIdx.x < N_) {
        const int n = blockIdx.x;
        const float* xr = x + (size_t)n * D_;
        float4 v0 = *(const float4*)(xr + t * 4);
        float4 v1 = *(const float4*)(xr + 1024 + t * 4);
        float s  = v0.x + v0.y + v0.z + v0.w + v1.x + v1.y + v1.z + v1.w;
        float sq = v0.x*v0.x + v0.y*v0.y + v0.z*v0.z + v0.w*v0.w
                 + v1.x*v1.x + v1.y*v1.y + v1.z*v1.z + v1.w*v1.w;
        #pragma unroll
        for (int o = 32; o > 0; o >>= 1) {
            s  += __shfl_xor(s,  o, 64);
            sq += __shfl_xor(sq, o, 64);
        }
        if ((t & 63) == 0) { sm[t >> 6] = s; sm[8 + (t >> 6)] = sq; }
        __syncthreads();
        s  = sm[0] + sm[1] + sm[2] + sm[3];
        sq = sm[8] + sm[9] + sm[10] + sm[11];
        const float mean = s * (1.0f / D_);
        const float var  = sq * (1.0f / D_) - mean * mean;
        const float rstd = rsqrtf(var + LN_EPS);

        ushort4 p0 = make_ushort4(f2bf((v0.x - mean) * rstd), f2bf((v0.y - mean) * rstd),
                                  f2bf((v0.z - mean) * rstd), f2bf((v0.w - mean) * rstd));
        ushort4 p1 = make_ushort4(f2bf((v1.x - mean) * rstd), f2bf((v1.y - mean) * rstd),
                                  f2bf((v1.z - mean) * rstd), f2bf((v1.w - mean) * rstd));
        *(ushort4*)(xhat + (size_t)n * D_ + t * 4)        = p0;
        *(ushort4*)(xhat + (size_t)n * D_ + 1024 + t * 4) = p1;
    } else {
        const int j = blockIdx.x - N_;
        const int r = j >> 7, a = j & 127;
        const float* Wc = W + (size_t)r * D_ * A_ + a;

        float vals[8];
        float s = 0.f, sq = 0.f;
        #pragma unroll
        for (int k = 0; k < 8; ++k) {
            float v = Wc[(size_t)(t + k * 256) * A_];
            vals[k] = v; s += v; sq += v * v;
        }
        #pragma unroll
        for (int o = 32; o > 0; o >>= 1) {
            s  += __shfl_xor(s,  o, 64);
            sq += __shfl_xor(sq, o, 64);
        }
        if ((t & 63) == 0) { sm[t >> 6] = s; sm[8 + (t >> 6)] = sq; }
        __syncthreads();
        s  = sm[0] + sm[1] + sm[2] + sm[3];
        sq = sm[8] + sm[9] + sm[10] + sm[11];
        const float mean = s * (1.0f / D_);
        const float var  = sq * (1.0f / D_) - mean * mean;
        const float rstd = rsqrtf(var + LN_EPS);

        float cp = 0.f;
        #pragma unroll
        for (int k = 0; k < 8; ++k) {
            const int d = t + k * 256;
            const float nv = (vals[k] - mean) * rstd * rw_w[(size_t)r * D_ + d]
                           + rw_b[(size_t)r * D_ + d];
            Bt[(size_t)j * D_ + d] = f2bf(ln_w[(size_t)r * D_ + d] * nv);
            cp += ln_b[(size_t)r * D_ + d] * nv;
        }
        __syncthreads();   // sm reuse
        #pragma unroll
        for (int o = 32; o > 0; o >>= 1) cp += __shfl_xor(cp, o, 64);
        if ((t & 63) == 0) sm[t >> 6] = cp;
        __syncthreads();
        if (t == 0) cvec[j] = sm[0] + sm[1] + sm[2] + sm[3] + rbias[(size_t)r * A_ + a];
    }
}

// ---------------------------------------------------------------------------
// k_fused: 1024 blocks = 128 m-tiles (64 rows) x 8 routers.
//   decode r = bid&7 (router == XCD: Bt[r] = 512 KB stays L2-resident — the
//   R2-vs-R5 A/B winner), mt = bid>>3 (same-mt blocks adjacent in dispatch
//   -> 8 XCDs read each xhat slab in the same time window -> L3 serves 7/8).
//   Per K-step: stage A(64x32)+B(128x32) via global_load_lds -> write the
//   new_x 64x32 fp32 slab (nontemporal: don't thrash L2/L3) -> 8 MFMA/wave.
//   Epilogue: bias + row-softmax, nontemporal stores.
// ---------------------------------------------------------------------------
__global__ __launch_bounds__(256) void k_fused(
    const ushort* __restrict__ Xh,
    const ushort* __restrict__ Bt,
    const float* __restrict__ cvec,
    const float* __restrict__ ln_w,
    const float* __restrict__ ln_b,
    float* __restrict__ new_x,
    float* __restrict__ logits,
    float* __restrict__ probs)
{
    __shared__ __attribute__((aligned(16))) ushort As[64 * 32];    // 4 KB
    __shared__ __attribute__((aligned(16))) ushort Bs[128 * 32];   // 8 KB
    __shared__ __attribute__((aligned(16))) float lwS[D_];         // 8 KB
    __shared__ __attribute__((aligned(16))) float lbS[D_];         // 8 KB

    const int t    = threadIdx.x;
    const int lane = t & 63;
    const int w    = t >> 6;             // wave 0..3, rows w*16..w*16+15
    const int r    = blockIdx.x & 7;     // router == XCD
    const int mt   = blockIdx.x >> 3;    // m-tile 0..127
    const int m0   = mt * 64;
    const int j0   = r * 128;

    // preload this router's LN params (16 KiB) — covered by first barrier
    #pragma unroll
    for (int i = 0; i < 2; ++i) {
        const int idx = t + i * 256;     // 512 float4 chunks each
        ((float4*)lwS)[idx] = ((const float4*)(ln_w + (size_t)r * D_))[idx];
        ((float4*)lbS)[idx] = ((const float4*)(ln_b + (size_t)r * D_))[idx];
    }

    f32x4 acc[8];
    #pragma unroll
    for (int jf = 0; jf < 8; ++jf) acc[jf] = (f32x4){0.f, 0.f, 0.f, 0.f};

    float* nx_base = new_x + ((size_t)r * N_ + m0) * D_;

    for (int kt = 0; kt < D_ / 32; ++kt) {
        __syncthreads();                 // prev iter's LDS reads done
        // stage A: 256 x 16B chunks (one per thread)
        {
            const int row = t >> 2;      // 0..63
            const int kc  = t & 3;
            const ushort* gA = Xh + (size_t)(m0 + row) * D_ + kt * 32 + kc * 8;
            __builtin_amdgcn_global_load_lds(
                (const __attribute__((address_space(1))) void*)gA,
                (__attribute__((address_space(3))) void*)(&As[t * 8]), 16, 0, 0);
        }
        // stage B: 512 chunks (two per thread)
        #pragma unroll
        for (int c = 0; c < 2; ++c) {
            const int q   = t + c * 256;
            const int row = q >> 2;      // 0..127
            const int kc  = q & 3;
            const ushort* gB = Bt + (size_t)(j0 + row) * D_ + kt * 32 + kc * 8;
            __builtin_amdgcn_global_load_lds(
                (const __attribute__((address_space(1))) void*)gB,
                (__attribute__((address_space(3))) void*)(&Bs[q * 8]), 16, 0, 0);
        }
        __syncthreads();                 // staging complete

        // new_x slab: 64 rows x 32 cols fp32; 2 f32x4 per thread,
        // 8 consecutive lanes cover one row's 128 B contiguously.
        const int kbase = kt * 32;
        #pragma unroll
        for (int c = 0; c < 2; ++c) {
            const int q    = t + c * 256;    // 0..511
            const int row  = q >> 3;         // 0..63
            const int col4 = q & 7;
            const int d    = kbase + col4 * 4;
            const ushort4 hb = *(const ushort4*)(&As[row * 32 + col4 * 4]);
            const float4 lw4 = *(const float4*)(&lwS[d]);
            const float4 lb4 = *(const float4*)(&lbS[d]);
            f32x4 o;
            o[0] = bf2f(hb.x) * lw4.x + lb4.x;
            o[1] = bf2f(hb.y) * lw4.y + lb4.y;
            o[2] = bf2f(hb.z) * lw4.z + lb4.z;
            o[3] = bf2f(hb.w) * lw4.w + lb4.w;
            __builtin_nontemporal_store(o, (f32x4*)(nx_base + (size_t)row * D_ + d));
        }

        // MFMA: wave w owns rows w*16..w*16+15 (1 A-frag x 8 B-frags)
        const bf16x8 afr = *(const bf16x8*)(&As[(w * 16 + (lane & 15)) * 32
                                                + (lane >> 4) * 8]);
        #pragma unroll
        for (int jf = 0; jf < 8; ++jf) {
            const bf16x8 bfr = *(const bf16x8*)(&Bs[(jf * 16 + (lane & 15)) * 32
                                                    + (lane >> 4) * 8]);
            acc[jf] = __builtin_amdgcn_mfma_f32_16x16x32_bf16(afr, bfr, acc[jf], 0, 0, 0);
        }
    }

    // Epilogue: bias + row softmax (j-range == router r's full A=128).
    // C/D layout: col = lane&15, row = (lane>>4)*4 + reg.
    float cv[8];
    #pragma unroll
    for (int jf = 0; jf < 8; ++jf) cv[jf] = cvec[j0 + jf * 16 + (lane & 15)];

    #pragma unroll
    for (int reg = 0; reg < 4; ++reg) {
        const int row = m0 + w * 16 + (lane >> 4) * 4 + reg;
        float v[8], e[8];
        float mx = -3.4e38f;
        #pragma unroll
        for (int jf = 0; jf < 8; ++jf) {
            v[jf] = acc[jf][reg] + cv[jf];
            mx = fmaxf(mx, v[jf]);
        }
        #pragma unroll
        for (int o = 8; o > 0; o >>= 1) mx = fmaxf(mx, __shfl_xor(mx, o, 64));
        float ssum = 0.f;
        #pragma unroll
        for (int jf = 0; jf < 8; ++jf) { e[jf] = __expf(v[jf] - mx); ssum += e[jf]; }
        #pragma unroll
        for (int o = 8; o > 0; o >>= 1) ssum += __shfl_xor(ssum, o, 64);
        const float inv = 1.0f / ssum;
        float* lrow = logits + ((size_t)r * N_ + row) * A_;
        float* prow = probs  + ((size_t)r * N_ + row) * A_;
        #pragma unroll
        for (int jf = 0; jf < 8; ++jf) {
            const int aa = jf * 16 + (lane & 15);
            __builtin_nontemporal_store(v[jf], lrow + aa);
            __builtin_nontemporal_store(e[jf] * inv, prow + aa);
        }
    }
}

// ---------------------------------------------------------------------------
extern "C" void kernel_launch(void* const* d_in, const int* in_sizes, int n_in,
                              void* d_out, int out_size, void* d_ws, size_t ws_size,
                              hipStream_t stream)
{
    const float* x     = (const float*)d_in[0];
    const float* ln_w  = (const float*)d_in[1];
    const float* ln_b  = (const float*)d_in[2];
    const float* W     = (const float*)d_in[3];
    const float* rw_w  = (const float*)d_in[4];
    const float* rw_b  = (const float*)d_in[5];
    const float* rbias = (const float*)d_in[6];

    float* out    = (float*)d_out;
    float* new_x  = out;                                   // [R,N,D]
    float* logits = out + (size_t)R_ * N_ * D_;            // [R,N,A]
    float* probs  = logits + (size_t)R_ * N_ * A_;         // [R,N,A]

    // ws: xhat bf16 [N][D] (32 MiB) | Bt bf16 [J][D] (4 MiB) | cvec f32 [J]
    ushort* xhat = (ushort*)d_ws;
    ushort* Btp  = (ushort*)((char*)d_ws + (size_t)N_ * D_ * 2);
    float*  cvec = (float*)((char*)d_ws + (size_t)N_ * D_ * 2 + (size_t)J_ * D_ * 2);

    hipLaunchKernelGGL(k_prep, dim3(N_ + J_), dim3(256), 0, stream,
                       x, W, ln_w, ln_b, rw_w, rw_b, rbias, xhat, Btp, cvec);
    hipLaunchKernelGGL(k_fused, dim3(J_), dim3(256), 0, stream,
                       xhat, Btp, cvec, ln_w, ln_b, new_x, logits, probs);
}

// Round 8
// 189.941 us; speedup vs baseline: 1.7970x; 1.0074x over previous
//
#include <hip/hip_runtime.h>
#include <hip/hip_bf16.h>
#include <stdint.h>

#define R_ 8
#define N_ 8192
#define D_ 2048
#define A_ 128
#define J_ 1024          // R_*A_
#define LN_EPS 1e-5f

typedef __attribute__((ext_vector_type(8))) short bf16x8;   // 8 bf16 in 4 VGPRs
typedef __attribute__((ext_vector_type(4))) float f32x4;

__device__ inline ushort f2bf(float f) {
    union { float f; uint32_t u; } v; v.f = f;
    uint32_t u = v.u;
    return (ushort)((u + 0x7fffu + ((u >> 16) & 1u)) >> 16);   // RNE
}
__device__ inline float bf2f(ushort u) {
    union { uint32_t u; float f; } v; v.u = ((uint32_t)u) << 16;
    return v.f;
}

// ---------------------------------------------------------------------------
// k_prep: blocks [0,N_)   : row-LN stats of x -> xhat bf16 (shared by routers)
//         blocks [N_,N_+J_): weight-LN column j -> Bt bf16 (K-major) + cvec
// ---------------------------------------------------------------------------
__global__ __launch_bounds__(256) void k_prep(
    const float* __restrict__ x,
    const float* __restrict__ W,
    const float* __restrict__ ln_w,
    const float* __restrict__ ln_b,
    const float* __restrict__ rw_w,
    const float* __restrict__ rw_b,
    const float* __restrict__ rbias,
    ushort* __restrict__ xhat,
    ushort* __restrict__ Bt,
    float* __restrict__ cvec)
{
    __shared__ float sm[16];
    const int t = threadIdx.x;

    if (blockIdx.x < N_) {
        const int n = blockIdx.x;
        const float* xr = x + (size_t)n * D_;
        float4 v0 = *(const float4*)(xr + t * 4);
        float4 v1 = *(const float4*)(xr + 1024 + t * 4);
        float s  = v0.x + v0.y + v0.z + v0.w + v1.x + v1.y + v1.z + v1.w;
        float sq = v0.x*v0.x + v0.y*v0.y + v0.z*v0.z + v0.w*v0.w
                 + v1.x*v1.x + v1.y*v1.y + v1.z*v1.z + v1.w*v1.w;
        #pragma unroll
        for (int o = 32; o > 0; o >>= 1) {
            s  += __shfl_xor(s,  o, 64);
            sq += __shfl_xor(sq, o, 64);
        }
        if ((t & 63) == 0) { sm[t >> 6] = s; sm[8 + (t >> 6)] = sq; }
        __syncthreads();
        s  = sm[0] + sm[1] + sm[2] + sm[3];
        sq = sm[8] + sm[9] + sm[10] + sm[11];
        const float mean = s * (1.0f / D_);
        const float var  = sq * (1.0f / D_) - mean * mean;
        const float rstd = rsqrtf(var + LN_EPS);

        ushort4 p0 = make_ushort4(f2bf((v0.x - mean) * rstd), f2bf((v0.y - mean) * rstd),
                                  f2bf((v0.z - mean) * rstd), f2bf((v0.w - mean) * rstd));
        ushort4 p1 = make_ushort4(f2bf((v1.x - mean) * rstd), f2bf((v1.y - mean) * rstd),
                                  f2bf((v1.z - mean) * rstd), f2bf((v1.w - mean) * rstd));
        *(ushort4*)(xhat + (size_t)n * D_ + t * 4)        = p0;
        *(ushort4*)(xhat + (size_t)n * D_ + 1024 + t * 4) = p1;
    } else {
        const int j = blockIdx.x - N_;
        const int r = j >> 7, a = j & 127;
        const float* Wc = W + (size_t)r * D_ * A_ + a;

        float vals[8];
        float s = 0.f, sq = 0.f;
        #pragma unroll
        for (int k = 0; k < 8; ++k) {
            float v = Wc[(size_t)(t + k * 256) * A_];
            vals[k] = v; s += v; sq += v * v;
        }
        #pragma unroll
        for (int o = 32; o > 0; o >>= 1) {
            s  += __shfl_xor(s,  o, 64);
            sq += __shfl_xor(sq, o, 64);
        }
        if ((t & 63) == 0) { sm[t >> 6] = s; sm[8 + (t >> 6)] = sq; }
        __syncthreads();
        s  = sm[0] + sm[1] + sm[2] + sm[3];
        sq = sm[8] + sm[9] + sm[10] + sm[11];
        const float mean = s * (1.0f / D_);
        const float var  = sq * (1.0f / D_) - mean * mean;
        const float rstd = rsqrtf(var + LN_EPS);

        float cp = 0.f;
        #pragma unroll
        for (int k = 0; k < 8; ++k) {
            const int d = t + k * 256;
            const float nv = (vals[k] - mean) * rstd * rw_w[(size_t)r * D_ + d]
                           + rw_b[(size_t)r * D_ + d];
            Bt[(size_t)j * D_ + d] = f2bf(ln_w[(size_t)r * D_ + d] * nv);
            cp += ln_b[(size_t)r * D_ + d] * nv;
        }
        __syncthreads();   // sm reuse
        #pragma unroll
        for (int o = 32; o > 0; o >>= 1) cp += __shfl_xor(cp, o, 64);
        if ((t & 63) == 0) sm[t >> 6] = cp;
        __syncthreads();
        if (t == 0) cvec[j] = sm[0] + sm[1] + sm[2] + sm[3] + rbias[(size_t)r * A_ + a];
    }
}

// ---------------------------------------------------------------------------
// k_fused: 1024 blocks = 128 m-tiles (64 rows) x 8 routers.
//   decode r = bid&7 (router == XCD: Bt[r] L2-resident), mt = bid>>3.
//   DOUBLE-BUFFERED 2-phase K-loop (T3 minimum recipe): per iter,
//   issue next tile's global_load_lds FIRST, then slab-stores + MFMA from
//   the current buffer, then ONE __syncthreads — the vmcnt drain at the
//   barrier happens a full compute-phase after issue, hiding the staging
//   latency that the old stage->drain->compute loop exposed every iter.
// ---------------------------------------------------------------------------
__global__ __launch_bounds__(256) void k_fused(
    const ushort* __restrict__ Xh,
    const ushort* __restrict__ Bt,
    const float* __restrict__ cvec,
    const float* __restrict__ ln_w,
    const float* __restrict__ ln_b,
    float* __restrict__ new_x,
    float* __restrict__ logits,
    float* __restrict__ probs)
{
    __shared__ __attribute__((aligned(16))) ushort As[2][64 * 32];    // 8 KB
    __shared__ __attribute__((aligned(16))) ushort Bs[2][128 * 32];   // 16 KB
    __shared__ __attribute__((aligned(16))) float lwS[D_];            // 8 KB
    __shared__ __attribute__((aligned(16))) float lbS[D_];            // 8 KB

    const int t    = threadIdx.x;
    const int lane = t & 63;
    const int w    = t >> 6;             // wave 0..3, rows w*16..w*16+15
    const int r    = blockIdx.x & 7;     // router == XCD
    const int mt   = blockIdx.x >> 3;    // m-tile 0..127
    const int m0   = mt * 64;
    const int j0   = r * 128;

    // staging helpers (one A chunk + two B chunks per thread per tile)
    const int arow = t >> 2, akc = t & 3;
    const ushort* gA0 = Xh + (size_t)(m0 + arow) * D_ + akc * 8;

    auto stage = [&](int buf, int kt) {
        __builtin_amdgcn_global_load_lds(
            (const __attribute__((address_space(1))) void*)(gA0 + kt * 32),
            (__attribute__((address_space(3))) void*)(&As[buf][t * 8]), 16, 0, 0);
        #pragma unroll
        for (int c = 0; c < 2; ++c) {
            const int q   = t + c * 256;
            const int row = q >> 2;      // 0..127
            const int kc  = q & 3;
            const ushort* gB = Bt + (size_t)(j0 + row) * D_ + kt * 32 + kc * 8;
            __builtin_amdgcn_global_load_lds(
                (const __attribute__((address_space(1))) void*)gB,
                (__attribute__((address_space(3))) void*)(&Bs[buf][q * 8]), 16, 0, 0);
        }
    };

    // preload this router's LN params (16 KiB)
    #pragma unroll
    for (int i = 0; i < 2; ++i) {
        const int idx = t + i * 256;
        ((float4*)lwS)[idx] = ((const float4*)(ln_w + (size_t)r * D_))[idx];
        ((float4*)lbS)[idx] = ((const float4*)(ln_b + (size_t)r * D_))[idx];
    }

    f32x4 acc[8];
    #pragma unroll
    for (int jf = 0; jf < 8; ++jf) acc[jf] = (f32x4){0.f, 0.f, 0.f, 0.f};

    float* nx_base = new_x + ((size_t)r * N_ + m0) * D_;

    stage(0, 0);
    __syncthreads();                     // tile 0 + params ready

    auto body = [&](int cur, int kt) {
        if (kt < 63) stage(cur ^ 1, kt + 1);    // issue next tile EARLY

        // new_x slab: 64 rows x 32 cols fp32; 2 f32x4 per thread.
        const int kbase = kt * 32;
        #pragma unroll
        for (int c = 0; c < 2; ++c) {
            const int q    = t + c * 256;    // 0..511
            const int row  = q >> 3;         // 0..63
            const int col4 = q & 7;
            const int d    = kbase + col4 * 4;
            const ushort4 hb = *(const ushort4*)(&As[cur][row * 32 + col4 * 4]);
            const float4 lw4 = *(const float4*)(&lwS[d]);
            const float4 lb4 = *(const float4*)(&lbS[d]);
            f32x4 o;
            o[0] = bf2f(hb.x) * lw4.x + lb4.x;
            o[1] = bf2f(hb.y) * lw4.y + lb4.y;
            o[2] = bf2f(hb.z) * lw4.z + lb4.z;
            o[3] = bf2f(hb.w) * lw4.w + lb4.w;
            __builtin_nontemporal_store(o, (f32x4*)(nx_base + (size_t)row * D_ + d));
        }

        // MFMA: wave w owns rows w*16..w*16+15 (1 A-frag x 8 B-frags)
        const bf16x8 afr = *(const bf16x8*)(&As[cur][(w * 16 + (lane & 15)) * 32
                                                     + (lane >> 4) * 8]);
        #pragma unroll
        for (int jf = 0; jf < 8; ++jf) {
            const bf16x8 bfr = *(const bf16x8*)(&Bs[cur][(jf * 16 + (lane & 15)) * 32
                                                         + (lane >> 4) * 8]);
            acc[jf] = __builtin_amdgcn_mfma_f32_16x16x32_bf16(afr, bfr, acc[jf], 0, 0, 0);
        }

        __syncthreads();                 // single drain per iter (loads landed
                                         // during the compute phase above)
    };

    for (int kt2 = 0; kt2 < 64; kt2 += 2) {
        body(0, kt2);
        body(1, kt2 + 1);
    }

    // Epilogue: bias + row softmax (j-range == router r's full A=128).
    // C/D layout: col = lane&15, row = (lane>>4)*4 + reg.
    float cv[8];
    #pragma unroll
    for (int jf = 0; jf < 8; ++jf) cv[jf] = cvec[j0 + jf * 16 + (lane & 15)];

    #pragma unroll
    for (int reg = 0; reg < 4; ++reg) {
        const int row = m0 + w * 16 + (lane >> 4) * 4 + reg;
        float v[8], e[8];
        float mx = -3.4e38f;
        #pragma unroll
        for (int jf = 0; jf < 8; ++jf) {
            v[jf] = acc[jf][reg] + cv[jf];
            mx = fmaxf(mx, v[jf]);
        }
        #pragma unroll
        for (int o = 8; o > 0; o >>= 1) mx = fmaxf(mx, __shfl_xor(mx, o, 64));
        float ssum = 0.f;
        #pragma unroll
        for (int jf = 0; jf < 8; ++jf) { e[jf] = __expf(v[jf] - mx); ssum += e[jf]; }
        #pragma unroll
        for (int o = 8; o > 0; o >>= 1) ssum += __shfl_xor(ssum, o, 64);
        const float inv = 1.0f / ssum;
        float* lrow = logits + ((size_t)r * N_ + row) * A_;
        float* prow = probs  + ((size_t)r * N_ + row) * A_;
        #pragma unroll
        for (int jf = 0; jf < 8; ++jf) {
            const int aa = jf * 16 + (lane & 15);
            __builtin_nontemporal_store(v[jf], lrow + aa);
            __builtin_nontemporal_store(e[jf] * inv, prow + aa);
        }
    }
}

// ---------------------------------------------------------------------------
extern "C" void kernel_launch(void* const* d_in, const int* in_sizes, int n_in,
                              void* d_out, int out_size, void* d_ws, size_t ws_size,
                              hipStream_t stream)
{
    const float* x     = (const float*)d_in[0];
    const float* ln_w  = (const float*)d_in[1];
    const float* ln_b  = (const float*)d_in[2];
    const float* W     = (const float*)d_in[3];
    const float* rw_w  = (const float*)d_in[4];
    const float* rw_b  = (const float*)d_in[5];
    const float* rbias = (const float*)d_in[6];

    float* out    = (float*)d_out;
    float* new_x  = out;                                   // [R,N,D]
    float* logits = out + (size_t)R_ * N_ * D_;            // [R,N,A]
    float* probs  = logits + (size_t)R_ * N_ * A_;         // [R,N,A]

    // ws: xhat bf16 [N][D] (32 MiB) | Bt bf16 [J][D] (4 MiB) | cvec f32 [J]
    ushort* xhat = (ushort*)d_ws;
    ushort* Btp  = (ushort*)((char*)d_ws + (size_t)N_ * D_ * 2);
    float*  cvec = (float*)((char*)d_ws + (size_t)N_ * D_ * 2 + (size_t)J_ * D_ * 2);

    hipLaunchKernelGGL(k_prep, dim3(N_ + J_), dim3(256), 0, stream,
                       x, W, ln_w, ln_b, rw_w, rw_b, rbias, xhat, Btp, cvec);
    hipLaunchKernelGGL(k_fused, dim3(J_), dim3(256), 0, stream,
                       xhat, Btp, cvec, ln_w, ln_b, new_x, logits, probs);
}